// Round 8
// baseline (14376.260 us; speedup 1.0000x reference)
//
#include <hip/hip_runtime.h>

// Seq2Seq round 8: round-7 design with compile fix (stray load8 arg).
// Fully block-local decoder (16 blocks x 8 samples, zero inter-block sync).

typedef unsigned short u16;
typedef __attribute__((ext_vector_type(8))) short bf16x8;
typedef __attribute__((ext_vector_type(4))) float f32x4;

#define DEVFN static __device__ __forceinline__

DEVFN float bf2f(u16 u) {
  unsigned int x = ((unsigned int)u) << 16;
  float f; __builtin_memcpy(&f, &x, 4); return f;
}
DEVFN u16 f2bf(float f) {
  unsigned int x; __builtin_memcpy(&x, &f, 4);
  x = (x + 0x7fffu + ((x >> 16) & 1u)) >> 16;
  return (u16)x;
}
DEVFN float sigf(float x) { return 1.f / (1.f + __expf(-x)); }
DEVFN bf16x8 load8(const u16* p) { return *(const bf16x8*)p; }
DEVFN int clampi(int v, int lo, int hi) { return v < lo ? lo : (v > hi ? hi : v); }

// ---------------------------------------------------------------------------
// Generic MFMA GEMM: out[m,n] = sum_k A[m,k]*W[n,k]. EPI 0: f32 (+bias). 1: bf16.
// ---------------------------------------------------------------------------
struct GemmArgs {
  const u16* A; int lda; int M;
  const u16* W; int ldw; int N; int K;
  void* out; int ldc;
  const float* bias;
};

template <int EPI>
__global__ __launch_bounds__(256) void gemm_k(GemmArgs g) {
  int lane = threadIdx.x & 63, wave = threadIdx.x >> 6;
  int col = lane & 15, q = lane >> 4;
  int m0 = blockIdx.x * 64 + (wave >> 1) * 32;
  int n0 = blockIdx.y * 64 + (wave & 1) * 32;
  f32x4 acc[2][2] = {};
  int rA[2] = { m0 + col, m0 + 16 + col };
  int rB[2] = { n0 + col, n0 + 16 + col };
  bool gA[2] = { rA[0] < g.M, rA[1] < g.M };
  bool gB[2] = { rB[0] < g.N, rB[1] < g.N };
  const u16* pA[2]; const u16* pB[2];
#pragma unroll
  for (int i = 0; i < 2; i++) {
    pA[i] = g.A + (size_t)(gA[i] ? rA[i] : 0) * g.lda + q * 8;
    pB[i] = g.W + (size_t)(gB[i] ? rB[i] : 0) * g.ldw + q * 8;
  }
  bf16x8 zf = {0,0,0,0,0,0,0,0};
  for (int k = 0; k < g.K; k += 32) {
    bf16x8 a0 = gA[0] ? load8(pA[0] + k) : zf;
    bf16x8 a1 = gA[1] ? load8(pA[1] + k) : zf;
    bf16x8 b0 = gB[0] ? load8(pB[0] + k) : zf;
    bf16x8 b1 = gB[1] ? load8(pB[1] + k) : zf;
    acc[0][0] = __builtin_amdgcn_mfma_f32_16x16x32_bf16(a0, b0, acc[0][0], 0, 0, 0);
    acc[0][1] = __builtin_amdgcn_mfma_f32_16x16x32_bf16(a0, b1, acc[0][1], 0, 0, 0);
    acc[1][0] = __builtin_amdgcn_mfma_f32_16x16x32_bf16(a1, b0, acc[1][0], 0, 0, 0);
    acc[1][1] = __builtin_amdgcn_mfma_f32_16x16x32_bf16(a1, b1, acc[1][1], 0, 0, 0);
  }
#pragma unroll
  for (int mi = 0; mi < 2; mi++)
#pragma unroll
    for (int ni = 0; ni < 2; ni++)
#pragma unroll
      for (int r = 0; r < 4; r++) {
        int m = m0 + mi * 16 + q * 4 + r;
        int n = n0 + ni * 16 + col;
        if (m >= g.M || n >= g.N) continue;
        float v = acc[mi][ni][r];
        if (g.bias) v += g.bias[n];
        if constexpr (EPI == 0) ((float*)g.out)[(size_t)m * g.ldc + n] = v;
        else ((u16*)g.out)[(size_t)m * g.ldc + n] = f2bf(v);
      }
}

// ---------------------------------------------------------------------------
// prep kernels
// ---------------------------------------------------------------------------
struct CvtAll {
  const float* src[13]; u16* dst[13];
  int R[13], C[13], ld[13], c0[13], mode[13], blk0[14];
};
__global__ __launch_bounds__(256) void cvt_all_k(CvtAll a) {
  int blk = blockIdx.x, s = 0;
  while (s < 12 && blk >= a.blk0[s + 1]) s++;
  int idx = (blk - a.blk0[s]) * 256 + threadIdx.x;
  int n = a.R[s] * a.C[s];
  if (idx >= n) return;
  int r = idx / a.C[s], c = idx - r * a.C[s];
  int sr = (a.mode[s] == 1) ? ((r & 3) * 256 + (r >> 2)) : r;  // gate interleave (enc)
  a.dst[s][idx] = f2bf(a.src[s][(size_t)sr * a.ld[s] + a.c0[s] + c]);
}

__global__ void smallprep(const float* bihf, const float* bhhf, const float* bihb, const float* bhhb,
                          const float* Wbdb, const float* h2ab, const float* dbih, const float* dbhh,
                          float* bias_f, float* bias_b, float* bwbd, float* bh2a, float* bdec) {
  int i = blockIdx.x * 256 + threadIdx.x;
  if (i < 1024) { int src = (i & 3) * 256 + (i >> 2); bias_f[i] = bihf[src] + bhhf[src]; }
  else if (i < 2048) { int r = i - 1024; int src = (r & 3) * 256 + (r >> 2); bias_b[r] = bihb[src] + bhhb[src]; }
  else if (i < 2560) { int k = i - 2048; bwbd[k] = Wbdb[k]; }
  else if (i < 2660) { int k = i - 2560; bh2a[k] = h2ab[k]; }
  else if (i < 4708) { int r = i - 2660; bdec[r] = dbih[r] + dbhh[r]; }
}

__global__ void wsum_build(const float* Wbd, u16* Wsum) {
  int idx = blockIdx.x * 256 + threadIdx.x;  // 512*896
  int n = idx / 896, j = idx % 896;
  int c1 = (j < 448) ? (1024 + j) : (1920 + (j - 448));
  int c2 = c1 + 448;
  Wsum[idx] = f2bf(Wbd[(size_t)n * 2944 + c1] + Wbd[(size_t)n * 2944 + c2]);
}

// ---------------------------------------------------------------------------
// Env encoder: 1792 4-step LSTM chains (hidden 32) -> ctx_cat(B,896) bf16
// ---------------------------------------------------------------------------
__global__ __launch_bounds__(256) void env_encode(
    const int* cur_env, const int* ini_env,
    const float* color_emb, const float* pos_emb,
    const float* wih, const float* whh, const float* bih, const float* bhh,
    u16* ctx_cat) {
  __shared__ float s_wih[128 * 33], s_whh[128 * 33], s_b[128], s_col[7 * 32];
  __shared__ float h_lds[8][33];
  int tid = threadIdx.x;
  for (int i = tid; i < 128 * 32; i += 256) {
    int r = i >> 5, k2 = i & 31;
    s_wih[r * 33 + k2] = wih[i];
    s_whh[r * 33 + k2] = whh[i];
  }
  for (int i = tid; i < 128; i += 256) s_b[i] = bih[i] + bhh[i];
  for (int i = tid; i < 224; i += 256) s_col[i] = color_emb[i];
  int sl = tid >> 5, j = tid & 31;
  int gseq = blockIdx.x * 8 + sl;
  int e = gseq / 896, rem = gseq % 896;
  int b = rem / 7, p = rem % 7;
  const int* env = e ? ini_env : cur_env;
  int eoff = e ? 0 : 448;
  h_lds[sl][j] = 0.f;
  __syncthreads();
  float cj = 0.f, hj = 0.f;
  for (int st = 0; st < 4; st++) {
    int tok = clampi(env[b * 35 + p * 5 + 1 + st], 0, 6);
    const float* x = &s_col[tok * 32];
    float pi = s_b[j], pf = s_b[32 + j], pg = s_b[64 + j], po = s_b[96 + j];
    for (int k = 0; k < 32; k++) {
      float xk = x[k], hk = h_lds[sl][k];
      pi += s_wih[j * 33 + k] * xk + s_whh[j * 33 + k] * hk;
      pf += s_wih[(32 + j) * 33 + k] * xk + s_whh[(32 + j) * 33 + k] * hk;
      pg += s_wih[(64 + j) * 33 + k] * xk + s_whh[(64 + j) * 33 + k] * hk;
      po += s_wih[(96 + j) * 33 + k] * xk + s_whh[(96 + j) * 33 + k] * hk;
    }
    cj = sigf(pf) * cj + sigf(pi) * tanhf(pg);
    hj = sigf(po) * tanhf(cj);
    __syncthreads();
    h_lds[sl][j] = hj;
    __syncthreads();
  }
  size_t base = (size_t)b * 896 + eoff + p * 64;
  ctx_cat[base + j] = f2bf(pos_emb[p * 32 + j]);
  ctx_cat[base + 32 + j] = f2bf(hj);
}

// ---------------------------------------------------------------------------
// Block-local persistent encoder: 32 blocks x 1024 thr.
// ---------------------------------------------------------------------------
__global__ __launch_bounds__(1024) void enc_persist(
    const int* ins_tok, const int* his_tok,
    const u16* whhf_int, const u16* whhb_int,
    const u16* projf, const u16* projb,
    u16* ins_enc, u16* his_enc) {
  int blk = blockIdx.x;
  int chain = blk >> 3, sgrp = blk & 7;
  int dir = chain & 1, his = chain >> 1;
  int L = his ? 128 : 64;
  const int* toks = his ? his_tok : ins_tok;
  const u16* whh = dir ? whhb_int : whhf_int;
  const u16* proj = dir ? projb : projf;
  u16* out = his ? his_enc : ins_enc;
  int tid = threadIdx.x;
  int wv = tid >> 6, lane = tid & 63, col = lane & 15, q = lane >> 4;
  __shared__ u16 s_h[16][264];
  __shared__ float s_st[16][16][4][17];
  __shared__ int s_tok[16];
  const u16* pB[4];
#pragma unroll
  for (int nt = 0; nt < 4; nt++)
    pB[nt] = whh + (size_t)(wv * 64 + nt * 16 + col) * 256 + q * 8;
  float c4[4] = {0.f, 0.f, 0.f, 0.f};
  int sm = lane & 15, jl = lane >> 4;
  for (int t = 0; t < L; t++) {
    int t_x = dir ? (L - 1 - t) : t;
    if (tid < 16) s_tok[tid] = clampi(toks[(sgrp * 16 + tid) * L + t_x], 0, 1999);
    __syncthreads();
    f32x4 acc[4] = {};
    if (t > 0) {
      bf16x8 af[8];
#pragma unroll
      for (int kt = 0; kt < 8; kt++)
        af[kt] = *(const bf16x8*)&s_h[col][kt * 32 + q * 8];
#pragma unroll
      for (int kt = 0; kt < 8; kt++)
#pragma unroll
        for (int nt = 0; nt < 4; nt++)
          acc[nt] = __builtin_amdgcn_mfma_f32_16x16x32_bf16(af[kt], load8(pB[nt] + kt * 32), acc[nt], 0, 0, 0);
    }
#pragma unroll
    for (int nt = 0; nt < 4; nt++)
#pragma unroll
      for (int r = 0; r < 4; r++)
        s_st[wv][q * 4 + r][nt][col] = acc[nt][r];
    __syncthreads();
    int tokv = s_tok[sm];
    const u16* prow = proj + (size_t)tokv * 1024;
#pragma unroll
    for (int nt = 0; nt < 4; nt++) {
      int j = wv * 16 + nt * 4 + jl;
      const u16* pp = prow + j * 4;
      float gi = s_st[wv][sm][nt][jl * 4 + 0] + bf2f(pp[0]);
      float gf = s_st[wv][sm][nt][jl * 4 + 1] + bf2f(pp[1]);
      float gg = s_st[wv][sm][nt][jl * 4 + 2] + bf2f(pp[2]);
      float go = s_st[wv][sm][nt][jl * 4 + 3] + bf2f(pp[3]);
      float cn = sigf(gf) * c4[nt] + sigf(gi) * tanhf(gg);
      c4[nt] = cn;
      u16 hb = f2bf(sigf(go) * tanhf(cn));
      s_h[sm][j] = hb;
      out[((size_t)(sgrp * 16 + sm) * L + t_x) * 512 + dir * 256 + j] = hb;
    }
  }
}

// ---------------------------------------------------------------------------
// Block-local decoder: 16 blocks x 512 thr (8 waves); block = 8 samples, all
// 32 steps inside, NO inter-block communication. wave=sample for attention.
// gates use plain n = g*512+j layout -> cell fully in-lane.
// ---------------------------------------------------------------------------
__global__ __launch_bounds__(512) void dec_local(
    const u16* insenc, const u16* hisenc,
    const u16* wc, const u16* wp, const u16* wbd,
    const u16* dwih, const u16* dwhh,
    const float* bdec, const float* hkbase, const float* projact,
    const int* actions, const float* h0, const float* c0,
    u16* outs) {
  int blk = blockIdx.x, tid = threadIdx.x;
  int wv = tid >> 6, lane = tid & 63, col = lane & 15, q = lane >> 4;
  int b0 = blk * 8;
  __shared__ u16 s_q[8][1048];    // [h(0:512) | z_c -> hk (512:1024)]
  __shared__ float s_u[8][520];   // u_c -> u_p -> (u16 view) z_p
  __shared__ float s_aw[8][136];
  __shared__ int s_act[8];

  int nbase = wv * 64;            // this wave's 64-wide N (and j) range
  int arow = col & 7;             // A-frag source row (M=8 duplicated to 16)
  bool vq = (q < 2);              // lanes holding valid C rows (m<8)
  int s = wv;                     // attention sample for this wave
  int d0 = lane * 8;

  unsigned ofsW[4];               // (nbase+nt*16+col)*512 + q*8   (wc)
  unsigned ofs1k[4];              // (nbase+nt*16+col)*1024 + q*8  (wp, wbd)
  unsigned ofsG[4][4];            // gates rows (g*512 + j-range)*512 + q*8
#pragma unroll
  for (int nt = 0; nt < 4; nt++) {
    int n = nbase + nt * 16 + col;
    ofsW[nt] = n * 512 + q * 8;
    ofs1k[nt] = n * 1024 + q * 8;
#pragma unroll
    for (int g = 0; g < 4; g++) ofsG[g][nt] = (g * 512 + n) * 512 + q * 8;
  }
  float bd[4][4], hkb[4][4], creg[4][4];
#pragma unroll
  for (int g = 0; g < 4; g++)
#pragma unroll
    for (int nt = 0; nt < 4; nt++)
      bd[g][nt] = bdec[g * 512 + nbase + nt * 16 + col];
  if (vq) {
#pragma unroll
    for (int nt = 0; nt < 4; nt++)
#pragma unroll
      for (int r = 0; r < 4; r++) {
        int m = q * 4 + r, n = nbase + nt * 16 + col;
        hkb[nt][r] = hkbase[(size_t)(b0 + m) * 512 + n];
        creg[nt][r] = c0[(size_t)(b0 + m) * 512 + n];
      }
  }
  // init h into s_q
  {
    const float* hp = h0 + (size_t)(b0 + wv) * 512 + d0;
#pragma unroll
    for (int e = 0; e < 8; e++) s_q[wv][d0 + e] = f2bf(hp[e]);
  }
  __syncthreads();

  for (int t = 0; t < 32; t++) {
    if (tid < 8) s_act[tid] = clampi(actions[(b0 + tid) * 32 + t], 0, 99);

    // ---- P1: u_c = W_c @ h (N=512, K=512) ----
    {
      f32x4 acc[4] = {};
      for (int k = 0; k < 512; k += 32) {
        bf16x8 a = *(const bf16x8*)&s_q[arow][k + q * 8];
#pragma unroll
        for (int nt = 0; nt < 4; nt++)
          acc[nt] = __builtin_amdgcn_mfma_f32_16x16x32_bf16(a, load8(wc + ofsW[nt] + k), acc[nt], 0, 0, 0);
      }
      if (vq)
#pragma unroll
        for (int nt = 0; nt < 4; nt++)
#pragma unroll
          for (int r = 0; r < 4; r++)
            s_u[q * 4 + r][nbase + nt * 16 + col] = acc[nt][r];
    }
    __syncthreads();

    // ---- P2: attn1 over ins (64 l; lane = l) ----
    {
      const u16* row = insenc + ((size_t)(b0 + s) * 64 + lane) * 512;
      float sc = 0.f;
      for (int k = 0; k < 512; k += 8) {
        bf16x8 v = load8(row + k);
#pragma unroll
        for (int e = 0; e < 8; e++) sc += bf2f((u16)v[e]) * s_u[s][k + e];
      }
      float m = sc;
      for (int off = 32; off > 0; off >>= 1) m = fmaxf(m, __shfl_xor(m, off));
      float ex = __expf(sc - m);
      float sm = ex;
      for (int off = 32; off > 0; off >>= 1) sm += __shfl_xor(sm, off);
      s_aw[s][lane] = ex / sm;
      // pass2: z_c (8 d per lane)
      float z[8] = {};
      const u16* base2 = insenc + (size_t)(b0 + s) * 64 * 512 + d0;
      for (int l = 0; l < 64; l++) {
        float a = s_aw[s][l];
        bf16x8 v = load8(base2 + l * 512);
#pragma unroll
        for (int e = 0; e < 8; e++) z[e] += a * bf2f((u16)v[e]);
      }
#pragma unroll
      for (int e = 0; e < 8; e++) s_q[s][512 + d0 + e] = f2bf(z[e]);
    }
    __syncthreads();

    // ---- P3: u_p = W_p @ [h|z_c] (N=512, K=1024) ----
    {
      f32x4 acc[4] = {};
      for (int k = 0; k < 1024; k += 32) {
        bf16x8 a = *(const bf16x8*)&s_q[arow][k + q * 8];
#pragma unroll
        for (int nt = 0; nt < 4; nt++)
          acc[nt] = __builtin_amdgcn_mfma_f32_16x16x32_bf16(a, load8(wp + ofs1k[nt] + k), acc[nt], 0, 0, 0);
      }
      if (vq)
#pragma unroll
        for (int nt = 0; nt < 4; nt++)
#pragma unroll
          for (int r = 0; r < 4; r++)
            s_u[q * 4 + r][nbase + nt * 16 + col] = acc[nt][r];
    }
    __syncthreads();

    // ---- P4: attn2 over his (128 l; lane = l, l+64) ----
    {
      const u16* row0 = hisenc + ((size_t)(b0 + s) * 128 + lane) * 512;
      const u16* row1 = row0 + 64 * 512;
      float sc0 = 0.f, sc1 = 0.f;
      for (int k = 0; k < 512; k += 8) {
        bf16x8 v0 = load8(row0 + k);
        bf16x8 v1 = load8(row1 + k);
#pragma unroll
        for (int e = 0; e < 8; e++) {
          float u = s_u[s][k + e];
          sc0 += bf2f((u16)v0[e]) * u;
          sc1 += bf2f((u16)v1[e]) * u;
        }
      }
      float m = fmaxf(sc0, sc1);
      for (int off = 32; off > 0; off >>= 1) m = fmaxf(m, __shfl_xor(m, off));
      float e0 = __expf(sc0 - m), e1 = __expf(sc1 - m);
      float sm = e0 + e1;
      for (int off = 32; off > 0; off >>= 1) sm += __shfl_xor(sm, off);
      s_aw[s][lane] = e0 / sm;
      s_aw[s][64 + lane] = e1 / sm;
      __syncthreads();  // all s_u (u_p) reads done before z_p overwrites it
      // pass2: z_p (8 d per lane) -> bf16 into s_u row (u16 view)
      float z[8] = {};
      const u16* base2 = hisenc + (size_t)(b0 + s) * 128 * 512 + d0;
      for (int l = 0; l < 128; l++) {
        float a = s_aw[s][l];
        bf16x8 v = load8(base2 + l * 512);
#pragma unroll
        for (int e = 0; e < 8; e++) z[e] += a * bf2f((u16)v[e]);
      }
      u16* zrow = (u16*)&s_u[s][0];
#pragma unroll
      for (int e = 0; e < 8; e++) zrow[d0 + e] = f2bf(z[e]);
    }
    __syncthreads();

    // ---- P5: hk = tanh(Wbd01 @ [z_c|z_p] + hkbase + projact[act]) ----
    {
      f32x4 acc[4] = {};
      for (int k = 0; k < 512; k += 32) {
        bf16x8 a = *(const bf16x8*)&s_q[arow][512 + k + q * 8];
#pragma unroll
        for (int nt = 0; nt < 4; nt++)
          acc[nt] = __builtin_amdgcn_mfma_f32_16x16x32_bf16(a, load8(wbd + ofs1k[nt] + k), acc[nt], 0, 0, 0);
      }
      const u16* zprow = (const u16*)&s_u[arow][0];
      for (int k = 0; k < 512; k += 32) {
        bf16x8 a = *(const bf16x8*)&zprow[k + q * 8];
#pragma unroll
        for (int nt = 0; nt < 4; nt++)
          acc[nt] = __builtin_amdgcn_mfma_f32_16x16x32_bf16(a, load8(wbd + ofs1k[nt] + 512 + k), acc[nt], 0, 0, 0);
      }
      __syncthreads();  // all z_c reads done before hk overwrite
      if (vq)
#pragma unroll
        for (int nt = 0; nt < 4; nt++)
#pragma unroll
          for (int r = 0; r < 4; r++) {
            int m = q * 4 + r, n = nbase + nt * 16 + col;
            float v = acc[nt][r] + hkb[nt][r] + projact[(size_t)s_act[m] * 512 + n];
            s_q[m][512 + n] = f2bf(tanhf(v));
          }
    }
    __syncthreads();

    // ---- P6: gates = Whh@h + Wih@hk (N=2048 plain), fused cell ----
    {
      f32x4 acc[4][4] = {};
      for (int k = 0; k < 512; k += 32) {
        bf16x8 a = *(const bf16x8*)&s_q[arow][k + q * 8];
#pragma unroll
        for (int g = 0; g < 4; g++)
#pragma unroll
          for (int nt = 0; nt < 4; nt++)
            acc[g][nt] = __builtin_amdgcn_mfma_f32_16x16x32_bf16(a, load8(dwhh + ofsG[g][nt] + k), acc[g][nt], 0, 0, 0);
      }
      for (int k = 0; k < 512; k += 32) {
        bf16x8 a = *(const bf16x8*)&s_q[arow][512 + k + q * 8];
#pragma unroll
        for (int g = 0; g < 4; g++)
#pragma unroll
          for (int nt = 0; nt < 4; nt++)
            acc[g][nt] = __builtin_amdgcn_mfma_f32_16x16x32_bf16(a, load8(dwih + ofsG[g][nt] + k), acc[g][nt], 0, 0, 0);
      }
      __syncthreads();  // all h reads done before h update
      if (vq)
#pragma unroll
        for (int nt = 0; nt < 4; nt++)
#pragma unroll
          for (int r = 0; r < 4; r++) {
            int sm_ = q * 4 + r;
            int j = nbase + nt * 16 + col;
            float gi = acc[0][nt][r] + bd[0][nt];
            float gf = acc[1][nt][r] + bd[1][nt];
            float gg = acc[2][nt][r] + bd[2][nt];
            float go = acc[3][nt][r] + bd[3][nt];
            float cn = sigf(gf) * creg[nt][r] + sigf(gi) * tanhf(gg);
            creg[nt][r] = cn;
            u16 hb = f2bf(sigf(go) * tanhf(cn));
            s_q[sm_][j] = hb;
            outs[((size_t)(b0 + sm_) * 32 + t) * 512 + j] = hb;
          }
    }
    __syncthreads();
  }
}

// ---------------------------------------------------------------------------
extern "C" void kernel_launch(void* const* d_in, const int* in_sizes, int n_in,
                              void* d_out, int out_size, void* d_ws, size_t ws_size,
                              hipStream_t stream) {
  const int* ins_tok = (const int*)d_in[0];
  const int* his_tok = (const int*)d_in[1];
  const int* actions = (const int*)d_in[2];
  const int* cur_env = (const int*)d_in[3];
  const int* ini_env = (const int*)d_in[4];
  const float* enc_emb = (const float*)d_in[5];
  const float* Wih_f = (const float*)d_in[6];
  const float* Whh_f = (const float*)d_in[7];
  const float* bih_f = (const float*)d_in[8];
  const float* bhh_f = (const float*)d_in[9];
  const float* Wih_b = (const float*)d_in[10];
  const float* Whh_b = (const float*)d_in[11];
  const float* bih_b = (const float*)d_in[12];
  const float* bhh_b = (const float*)d_in[13];
  const float* color_emb = (const float*)d_in[14];
  const float* pos_emb = (const float*)d_in[15];
  const float* ws_Wih = (const float*)d_in[16];
  const float* ws_Whh = (const float*)d_in[17];
  const float* ws_bih = (const float*)d_in[18];
  const float* ws_bhh = (const float*)d_in[19];
  const float* act_emb = (const float*)d_in[20];
  const float* W_c = (const float*)d_in[21];
  const float* W_p = (const float*)d_in[22];
  const float* Wbd_W = (const float*)d_in[27];
  const float* Wbd_b = (const float*)d_in[28];
  const float* dec_Wih = (const float*)d_in[29];
  const float* dec_Whh = (const float*)d_in[30];
  const float* dec_bih = (const float*)d_in[31];
  const float* dec_bhh = (const float*)d_in[32];
  const float* h2a_W = (const float*)d_in[33];
  const float* h2a_b = (const float*)d_in[34];
  const float* h0 = (const float*)d_in[35];
  const float* c0 = (const float*)d_in[36];
  (void)in_sizes; (void)n_in; (void)out_size; (void)ws_size;

  char* ws = (char*)d_ws;
  size_t off = 0;
  auto alloc = [&](size_t bytes) -> char* {
    char* p = ws + off;
    off = (off + bytes + 255) & ~(size_t)255;
    return p;
  };
  u16* insenc   = (u16*)alloc(8192ull * 512 * 2);
  u16* hisenc   = (u16*)alloc(16384ull * 512 * 2);
  u16* outs     = (u16*)alloc(4096ull * 512 * 2);
  u16* projf    = (u16*)alloc(2000ull * 1024 * 2);
  u16* projb    = (u16*)alloc(2000ull * 1024 * 2);
  u16* Wsum     = (u16*)alloc(512ull * 896 * 2);
  float* projact= (float*)alloc(100ull * 512 * 4);
  float* bias_f = (float*)alloc(1024 * 4);
  float* bias_b = (float*)alloc(1024 * 4);
  float* bdec   = (float*)alloc(2048 * 4);
  float* bwbd   = (float*)alloc(512 * 4);
  float* bh2a   = (float*)alloc(128 * 4);
  u16* ctxcat   = (u16*)alloc(128ull * 896 * 2);
  float* hkbase = (float*)alloc(128ull * 512 * 4);
  u16* emb_bf   = (u16*)alloc(2000ull * 128 * 2);
  u16* wihf_int = (u16*)alloc(1024ull * 128 * 2);
  u16* wihb_int = (u16*)alloc(1024ull * 128 * 2);
  u16* whhf_int = (u16*)alloc(1024ull * 256 * 2);
  u16* whhb_int = (u16*)alloc(1024ull * 256 * 2);
  u16* act_bf   = (u16*)alloc(100ull * 128 * 2);
  u16* wc_bf    = (u16*)alloc(512ull * 512 * 2);
  u16* wp_bf    = (u16*)alloc(512ull * 1024 * 2);
  u16* wbd01_bf = (u16*)alloc(512ull * 1024 * 2);
  u16* wbdx_bf  = (u16*)alloc(512ull * 128 * 2);
  u16* dwih_bf  = (u16*)alloc(2048ull * 512 * 2);
  u16* dwhh_bf  = (u16*)alloc(2048ull * 512 * 2);
  u16* h2a_bf   = (u16*)alloc(100ull * 512 * 2);

  // --- weight conversion (13 tensors; mode 1 = gate-interleave for encoder) ---
  CvtAll ca{};
  const float* srcs[13] = {enc_emb, Wih_f, Wih_b, Whh_f, Whh_b, act_emb,
                           W_c, W_p, Wbd_W, Wbd_W, dec_Wih, dec_Whh, h2a_W};
  u16* dsts[13] = {emb_bf, wihf_int, wihb_int, whhf_int, whhb_int, act_bf,
                   wc_bf, wp_bf, wbd01_bf, wbdx_bf, dwih_bf, dwhh_bf, h2a_bf};
  int Rs[13]  = {2000, 1024, 1024, 1024, 1024, 100, 512, 512, 512, 512, 2048, 2048, 100};
  int Cs[13]  = {128, 128, 128, 256, 256, 128, 512, 1024, 1024, 128, 512, 512, 512};
  int ldsv[13]= {128, 128, 128, 256, 256, 128, 512, 1024, 2944, 2944, 512, 512, 512};
  int c0s[13] = {0, 0, 0, 0, 0, 0, 0, 0, 0, 2816, 0, 0, 0};
  int mds[13] = {0, 1, 1, 1, 1, 0, 0, 0, 0, 0, 0, 0, 0};
  int blkacc = 0;
  for (int sidx = 0; sidx < 13; sidx++) {
    ca.src[sidx] = srcs[sidx]; ca.dst[sidx] = dsts[sidx];
    ca.R[sidx] = Rs[sidx]; ca.C[sidx] = Cs[sidx]; ca.ld[sidx] = ldsv[sidx];
    ca.c0[sidx] = c0s[sidx]; ca.mode[sidx] = mds[sidx];
    ca.blk0[sidx] = blkacc;
    blkacc += (Rs[sidx] * Cs[sidx] + 255) / 256;
  }
  ca.blk0[13] = blkacc;
  cvt_all_k<<<blkacc, 256, 0, stream>>>(ca);
  smallprep<<<19, 256, 0, stream>>>(bih_f, bhh_f, bih_b, bhh_b, Wbd_b, h2a_b,
                                    dec_bih, dec_bhh, bias_f, bias_b, bwbd, bh2a, bdec);
  wsum_build<<<1792, 256, 0, stream>>>(Wbd_W, Wsum);
  env_encode<<<224, 256, 0, stream>>>(cur_env, ini_env, color_emb, pos_emb,
                                      ws_Wih, ws_Whh, ws_bih, ws_bhh, ctxcat);

  // --- proj tables / projact / hkbase ---
  GemmArgs gf = {emb_bf, 128, 2000, wihf_int, 128, 1024, 128, projf, 1024, bias_f};
  gemm_k<1><<<dim3(32, 16), 256, 0, stream>>>(gf);
  GemmArgs gbk = {emb_bf, 128, 2000, wihb_int, 128, 1024, 128, projb, 1024, bias_b};
  gemm_k<1><<<dim3(32, 16), 256, 0, stream>>>(gbk);
  GemmArgs gp = {act_bf, 128, 100, wbdx_bf, 128, 512, 128, projact, 512, bwbd};
  gemm_k<0><<<dim3(2, 8), 256, 0, stream>>>(gp);
  GemmArgs gh = {ctxcat, 896, 128, Wsum, 896, 512, 896, hkbase, 512, nullptr};
  gemm_k<0><<<dim3(2, 8), 256, 0, stream>>>(gh);

  // --- encoder ---
  enc_persist<<<32, 1024, 0, stream>>>(ins_tok, his_tok, whhf_int, whhb_int,
                                       projf, projb, insenc, hisenc);

  // --- decoder (block-local, no inter-block sync) ---
  dec_local<<<16, 512, 0, stream>>>(insenc, hisenc, wc_bf, wp_bf, wbd01_bf,
                                    dwih_bf, dwhh_bf, bdec, hkbase, projact,
                                    actions, h0, c0, outs);

  // --- logits ---
  GemmArgs gl = {outs, 512, 4096, h2a_bf, 512, 100, 512, d_out, 100, bh2a};
  gemm_k<0><<<dim3(64, 2), 256, 0, stream>>>(gl);
}